// Round 2
// baseline (208.260 us; speedup 1.0000x reference)
//
#include <hip/hip_runtime.h>
#include <hip/hip_bf16.h>

// Problem constants (fixed by the reference)
#define CS     128
#define EDIM   256
#define NBATCH 2
#define TLEN   8192
#define NCHUNK 64
#define LEXT   1024
#define KSEL   7

typedef __attribute__((ext_vector_type(8)))  short short8;    // 8 bf16 = 4 VGPR (MFMA A/B frag)
typedef __attribute__((ext_vector_type(4)))  float floatx4;   // 16x16 MFMA C/D frag
typedef __attribute__((ext_vector_type(16))) float floatx16;  // 32x32 MFMA C/D frag

__device__ inline short bf16_of(float f) {
    __hip_bfloat16 h = __float2bfloat16(f);
    return *(short*)&h;
}
__device__ inline float f_of_bf16(short s) {
    __hip_bfloat16 h = *(__hip_bfloat16*)&s;
    return __bfloat162float(h);
}

// async global->LDS, 16B per lane; LDS dest = wave-uniform base + lane*16
__device__ inline void gl_lds16(const void* g, void* l) {
    __builtin_amdgcn_global_load_lds(
        (const __attribute__((address_space(1))) unsigned int*)g,
        (__attribute__((address_space(3))) unsigned int*)l, 16, 0, 0);
}

// raw barrier (no compiler vmcnt(0) drain) — counted vmcnt crosses it
#define RAW_BAR() asm volatile("s_barrier" ::: "memory")

// ---------------------------------------------------------------------------
// Fused prep: one x read -> cn_hi/cn_lo (k-sliced layout) + xt_hi ;
// 8 tail blocks convert dp.
// NEW cn layout: [b][chunk 64][ks 16][row 128][k 16] shorts — each (ks) tile
// of a chunk is one contiguous 4 KB block, so scores' gl_lds staging is a
// straight contiguous copy (perfect coalescing, zero-swizzle LDS).
// ---------------------------------------------------------------------------
__global__ __launch_bounds__(256) void prep_kernel(const float* __restrict__ x,
                                                   const float* __restrict__ dp,
                                                   short* __restrict__ cn_hi,
                                                   short* __restrict__ cn_lo,
                                                   short* __restrict__ xt_hi,
                                                   short* __restrict__ dp_hi) {
    const int bx = blockIdx.x;
    if (bx >= 256) {            // dp conversion: 8 blocks x 256 thr x 16 float4
        int t = (bx - 256) * 256 + threadIdx.x;
#pragma unroll
        for (int u = 0; u < 16; ++u) {
            int idx = (t * 16 + u) * 4;
            float4 v = *(const float4*)(dp + idx);
            *(short4*)(dp_hi + idx) =
                make_short4(bf16_of(v.x), bf16_of(v.y), bf16_of(v.z), bf16_of(v.w));
        }
        return;
    }

    __shared__ float tile[64 * 257];   // [t-row][e], pitch 257
    __shared__ float rnbuf[64];
    const int b = bx >> 7, t0 = (bx & 127) * 64;
    const int tid = threadIdx.x;
    const int r = tid >> 2, q = tid & 3;   // row r (0..63), quarter q (64 elems)

    const float* src = x + ((size_t)(b * TLEN + t0 + r)) * EDIM + q * 64;
    float* trow = &tile[r * 257 + q * 64];
    float s = 0.f;
#pragma unroll
    for (int u = 0; u < 16; ++u) {
        float4 v = *(const float4*)(src + u * 4);
        s += v.x * v.x + v.y * v.y + v.z * v.z + v.w * v.w;
        trow[u * 4 + 0] = v.x; trow[u * 4 + 1] = v.y;
        trow[u * 4 + 2] = v.z; trow[u * 4 + 3] = v.w;
    }
    s += __shfl_xor(s, 1);
    s += __shfl_xor(s, 2);
    const float rn = 1.0f / (sqrtf(s) + 1e-6f);
    if (q == 0) rnbuf[r] = rn;
    __syncthreads();

    // xt_hi write (unchanged layout [b][e][T])
    const int g16 = tid >> 4, tq = tid & 15;
#pragma unroll
    for (int it = 0; it < 16; ++it) {
        int e = g16 + it * 16;
        short hs2[4];
#pragma unroll
        for (int g = 0; g < 4; ++g)
            hs2[g] = bf16_of(tile[(tq * 4 + g) * 257 + e]);
        *(short4*)(xt_hi + ((size_t)(b * EDIM + e)) * TLEN + t0 + tq * 4)
            = make_short4(hs2[0], hs2[1], hs2[2], hs2[3]);
    }

    // cn write, k-sliced layout. thread (ks = tid>>4, l16 = tid&15) writes
    // rows l16, l16+16, l16+32, l16+48 of slice ks: 16 lanes x 32 B contiguous.
    const int chunk = t0 >> 7, half = (t0 >> 6) & 1;
    const size_t cbase = ((size_t)(b * 64 + chunk)) * 32768 + (size_t)half * 1024;
    const int ks = tid >> 4, l16 = tid & 15;
#pragma unroll
    for (int rr = 0; rr < 4; ++rr) {
        int lrow = rr * 16 + l16;
        float rnv = rnbuf[lrow];
        short8 h0, h1, l0, l1;
#pragma unroll
        for (int k2 = 0; k2 < 16; ++k2) {
            float c = tile[lrow * 257 + ks * 16 + k2] * rnv;
            short hh = bf16_of(c);
            short ll = bf16_of(c - f_of_bf16(hh));
            if (k2 < 8) { h0[k2] = hh; l0[k2] = ll; }
            else        { h1[k2 - 8] = hh; l1[k2 - 8] = ll; }
        }
        size_t o = cbase + (size_t)ks * 2048 + (size_t)lrow * 16;
        *(short8*)(cn_hi + o)     = h0;
        *(short8*)(cn_hi + o + 8) = h1;
        *(short8*)(cn_lo + o)     = l0;
        *(short8*)(cn_lo + o + 8) = l1;
    }
}

// ---------------------------------------------------------------------------
// Stage B v3: split-bf16 cosine scores with 32x32x16 MFMA, K-step 16.
//  - tiles are 4 KB each (contiguous in global thanks to k-sliced cn layout)
//    -> staging is a straight contiguous gl_lds copy, no swizzle
//  - frag reads: row = lane&31, k-half = lane>>5 -> 64 lanes read 64
//    consecutive 16B granules = bank-conflict-free by construction
//  - 2-buffer LDS = 32 KB -> 4 blocks/CU (launch_bounds(256,4))
//  - counted vmcnt(4) crosses raw barriers (T3/T4), setprio around MFMA (T5)
// C/D layout (verified, m74/m101): col = lane&31,
// row = (reg&3) + 8*(reg>>2) + 4*(lane>>5).
// ---------------------------------------------------------------------------
__global__ __launch_bounds__(256, 4) void scores_mfma(const short* __restrict__ cn_hi,
                                                      const short* __restrict__ cn_lo,
                                                      float* __restrict__ scores) {
    __shared__ short tiles[2][4][2048];         // [buf][Ah,Al,Bh,Bl][row*16+k] 32 KB
    double* red2   = (double*)&tiles[0][0][0];  // alias (epilogue only)
    float*  redbuf = (float*)&tiles[0][0][8];   // alias, bytes [16, 1040)

    const int p = blockIdx.x, b = blockIdx.y;
    int i = (int)((1.0f + sqrtf(1.0f + 8.0f * (float)p)) * 0.5f);
    while (i * (i - 1) / 2 > p) --i;
    while (i * (i + 1) / 2 <= p) ++i;
    const int j = p - i * (i - 1) / 2;

    const int tid  = threadIdx.x;
    const int w    = tid >> 6, lane = tid & 63;
    const int wr   = w >> 1, wc = w & 1;
    const int hi   = lane >> 5, l31 = lane & 31;

    const short* sarr  = (w & 1) ? cn_lo : cn_hi;
    const size_t sbase = ((size_t)b * 64 + ((w >> 1) ? j : i)) * 32768;
    const short* gsrc0 = sarr + sbase + lane * 8;   // per-lane contiguous

    // wave w stages its own 4 KB tile (Ah/Al/Bh/Bl) with 4 contiguous gl_lds
    auto stage = [&](int ks, int bf) {
        const short* g = gsrc0 + ks * 2048;
        short* ldst = &tiles[bf][w][0];
#pragma unroll
        for (int t = 0; t < 4; ++t)
            gl_lds16(g + t * 512, ldst + t * 512);
    };

    floatx16 acc[2][2];
#pragma unroll
    for (int rt = 0; rt < 2; ++rt)
#pragma unroll
        for (int ct = 0; ct < 2; ++ct)
#pragma unroll
            for (int reg = 0; reg < 16; ++reg) acc[rt][ct][reg] = 0.f;

    stage(0, 0);
    int buf = 0;
    for (int ks = 0; ks < 16; ++ks) {
        if (ks < 15) {
            stage(ks + 1, buf ^ 1);                           // 4 loads in flight
            asm volatile("s_waitcnt vmcnt(4)" ::: "memory");  // old 4 landed
        } else {
            asm volatile("s_waitcnt vmcnt(0)" ::: "memory");
        }
        RAW_BAR();   // all waves' current-buf tiles have landed

        short8 bh[2], bl[2];
#pragma unroll
        for (int ct = 0; ct < 2; ++ct) {
            int rb = wc * 64 + ct * 32 + l31;
            bh[ct] = *(const short8*)&tiles[buf][2][rb * 16 + hi * 8];
            bl[ct] = *(const short8*)&tiles[buf][3][rb * 16 + hi * 8];
        }
        __builtin_amdgcn_s_setprio(1);
#pragma unroll
        for (int rt = 0; rt < 2; ++rt) {
            int ra = wr * 64 + rt * 32 + l31;
            short8 ah = *(const short8*)&tiles[buf][0][ra * 16 + hi * 8];
            short8 al = *(const short8*)&tiles[buf][1][ra * 16 + hi * 8];
#pragma unroll
            for (int ct = 0; ct < 2; ++ct) {
                acc[rt][ct] = __builtin_amdgcn_mfma_f32_32x32x16_bf16(ah, bh[ct], acc[rt][ct], 0, 0, 0);
                acc[rt][ct] = __builtin_amdgcn_mfma_f32_32x32x16_bf16(ah, bl[ct], acc[rt][ct], 0, 0, 0);
                acc[rt][ct] = __builtin_amdgcn_mfma_f32_32x32x16_bf16(al, bh[ct], acc[rt][ct], 0, 0, 0);
            }
        }
        __builtin_amdgcn_s_setprio(0);
        RAW_BAR();   // all waves done reading buf before next stage overwrites
        buf ^= 1;
    }

    // epilogue: per-row max over 128 cols, then sum of row-maxes
#pragma unroll
    for (int rt = 0; rt < 2; ++rt) {
        float m[16];
#pragma unroll
        for (int reg = 0; reg < 16; ++reg)
            m[reg] = fmaxf(acc[rt][0][reg], acc[rt][1][reg]);
#pragma unroll
        for (int off = 1; off < 32; off <<= 1)
#pragma unroll
            for (int reg = 0; reg < 16; ++reg)
                m[reg] = fmaxf(m[reg], __shfl_xor(m[reg], off));
        if ((lane & 31) == 0) {
#pragma unroll
            for (int reg = 0; reg < 16; ++reg) {
                int rowin = (reg & 3) + 8 * (reg >> 2) + 4 * hi;
                redbuf[wc * 128 + wr * 64 + rt * 32 + rowin] = m[reg];
            }
        }
    }
    __syncthreads();

    double part = 0.0;
    if (tid < 128) part = (double)fmaxf(redbuf[tid], redbuf[128 + tid]);
#pragma unroll
    for (int off = 1; off < 64; off <<= 1) part += __shfl_xor(part, off);
    if (lane == 0 && w < 2) red2[w] = part;
    __syncthreads();
    if (tid == 0) scores[(b * NCHUNK + i) * NCHUNK + j] = (float)(red2[0] + red2[1]);
}

// ---------------------------------------------------------------------------
// Stage D v7: out = dp @ ext + chunk, single-pass bf16 MFMA, inlined top-k.
// K=64 steps (2 k32 sub-slices each), 3 LDS buffers, prefetch depth 2,
// ONE raw barrier per step (3 buffers make the trailing barrier redundant:
// any wave past BAR(st) implies all waves finished compute(st-1), and
// stage(st+2) overwrites exactly buf (st-1)%3). Counted per-wave vmcnt.
// Tile layout + XOR swizzle identical to the proven r12 version.
// ---------------------------------------------------------------------------
__global__ __launch_bounds__(256) void out_mfma(const float* __restrict__ x,
                                                const short* __restrict__ dph,
                                                const short* __restrict__ xth,
                                                const float* __restrict__ scores,
                                                float* __restrict__ out) {
    __shared__ short As[3][2][128 * 32];   // [buf][sub][c][k]  48 KB
    __shared__ short Bs[3][2][64 * 32];    // [buf][sub][e][k]  24 KB
    __shared__ int   slist[8], sslot[8], snum;
    __shared__ float swei[8];

    const int eq = blockIdx.x, n = blockIdx.y, b = blockIdx.z;
    const int e0 = eq * 64;
    const int tid  = threadIdx.x;
    const int w    = tid >> 6, lane = tid & 63;
    const int wr   = w >> 1, wc = w & 1;
    const int quad = lane >> 4, l15 = lane & 15;
    const int rr   = lane >> 2;
    const int c16  = (lane & 3) * 8;
    const int csw  = c16 ^ (((rr >> 1) & 3) * 8);
    const int q8   = (quad ^ ((l15 >> 1) & 3)) * 8;

    // ---- inlined top-7 (wave 0): candidates j in [0, n) ----
    if (w == 0) {
        const float* srow = scores + (b * NCHUNK + n) * NCHUNK;
        const int nsel = n < KSEL ? n : KSEL;
        float v = (lane < n) ? srow[lane] : -3.0e38f;
        float vals[KSEL];
        int   idxs[KSEL];
        for (int s2 = 0; s2 < nsel; ++s2) {
            float bv = v; int bi = lane;
#pragma unroll
            for (int off = 1; off < 64; off <<= 1) {
                float ov = __shfl_xor(bv, off);
                int   oi = __shfl_xor(bi, off);
                if (ov > bv || (ov == bv && oi < bi)) { bv = ov; bi = oi; }
            }
            vals[s2] = bv; idxs[s2] = bi;
            if (lane == bi) v = -3.0e38f;
        }
        if (lane == 0) {
            float vmin = (nsel > 0) ? vals[nsel - 1] : 0.0f;
            float inv  = 1.0f / (vmin + 1e-6f);
            int shift  = KSEL - nsel;
            int c = 0;
            for (int s2 = 0; s2 < 8; ++s2) {
                int jj; float ww;
                if (s2 < KSEL) {
                    int tt = s2 - shift;
                    if (tt >= 0) { jj = idxs[tt]; ww = vals[tt] * inv; }
                    else         { jj = -1;       ww = 0.0f; }
                } else { jj = n; ww = 1.0f; }
                if (jj >= 0) { slist[c] = jj; sslot[c] = s2; swei[c] = ww; ++c; }
            }
            snum = c;
        }
    }
    __syncthreads();
    const int NT = snum * 2;   // K=64 steps (2 k32 sub-slices per step)

    // stage step st into buffer b3: waves 0-1 stage As (8 loads), 2-3 Bs (4)
    auto stage = [&](int st, int b3) {
        int sv = st >> 1, kh = st & 1;
        if (w < 2) {
#pragma unroll
            for (int sub = 0; sub < 2; ++sub) {
                const short* gsrc = dph + (size_t)(sslot[sv] * 128 + (kh * 2 + sub) * 32) + csw;
#pragma unroll
                for (int t = 0; t < 4; ++t)
                    gl_lds16(gsrc + (size_t)(w * 64 + t * 16 + rr) * LEXT,
                             &As[b3][sub][(w * 64 + t * 16) * 32]);
            }
        } else {
#pragma unroll
            for (int sub = 0; sub < 2; ++sub) {
                const short* gsrc = xth + ((size_t)(b * EDIM + e0)) * TLEN
                                    + (size_t)(slist[sv] * CS + (kh * 2 + sub) * 32) + csw;
#pragma unroll
                for (int t = 0; t < 2; ++t)
                    gl_lds16(gsrc + (size_t)((w - 2) * 32 + t * 16 + rr) * TLEN,
                             &Bs[b3][sub][((w - 2) * 32 + t * 16) * 32]);
            }
        }
    };

    floatx4 accT[4][2], accP[4][2];
#pragma unroll
    for (int rt = 0; rt < 4; ++rt)
#pragma unroll
        for (int ct = 0; ct < 2; ++ct) accT[rt][ct] = (floatx4){0.f, 0.f, 0.f, 0.f};

    stage(0, 0);
    if (NT > 1) stage(1, 1);
    // ensure stage 0 landed (allow stage 1's loads to remain in flight)
    if (w < 2) asm volatile("s_waitcnt vmcnt(8)" ::: "memory");
    else       asm volatile("s_waitcnt vmcnt(4)" ::: "memory");

    int cur = 0;
    for (int st = 0; st < NT; ++st) {
        RAW_BAR();   // all waves: buf 'cur' landed, and compute(st-1) finished

        if ((st & 1) == 0) {
#pragma unroll
            for (int rt = 0; rt < 4; ++rt)
#pragma unroll
                for (int ct = 0; ct < 2; ++ct) accP[rt][ct] = (floatx4){0.f, 0.f, 0.f, 0.f};
        }

#pragma unroll
        for (int sub = 0; sub < 2; ++sub) {
            short8 bh[2];
#pragma unroll
            for (int ct = 0; ct < 2; ++ct) {
                int e = wc * 32 + ct * 16 + l15;
                bh[ct] = *(const short8*)&Bs[cur][sub][e * 32 + q8];
            }
            __builtin_amdgcn_s_setprio(1);
#pragma unroll
            for (int rt = 0; rt < 4; ++rt) {
                int r = wr * 64 + rt * 16 + l15;
                short8 ah = *(const short8*)&As[cur][sub][r * 32 + q8];
#pragma unroll
                for (int ct = 0; ct < 2; ++ct)
                    accP[rt][ct] = __builtin_amdgcn_mfma_f32_16x16x32_bf16(ah, bh[ct], accP[rt][ct], 0, 0, 0);
            }
            __builtin_amdgcn_s_setprio(0);
        }

        if ((st & 1) == 1) {
            float wcur = swei[st >> 1];
#pragma unroll
            for (int rt = 0; rt < 4; ++rt)
#pragma unroll
                for (int ct = 0; ct < 2; ++ct)
#pragma unroll
                    for (int reg = 0; reg < 4; ++reg)
                        accT[rt][ct][reg] += wcur * accP[rt][ct][reg];
        }

        if (st + 2 < NT) {
            int tgt = cur ? cur - 1 : 2;        // (cur+2)%3
            stage(st + 2, tgt);
            if (w < 2) asm volatile("s_waitcnt vmcnt(8)" ::: "memory");
            else       asm volatile("s_waitcnt vmcnt(4)" ::: "memory");
        } else if (st + 1 < NT) {
            asm volatile("s_waitcnt vmcnt(0)" ::: "memory");
        }
        cur = (cur == 2) ? 0 : cur + 1;
    }

#pragma unroll
    for (int rt = 0; rt < 4; ++rt)
#pragma unroll
        for (int ct = 0; ct < 2; ++ct) {
#pragma unroll
            for (int reg = 0; reg < 4; ++reg) {
                int row = wr * 64 + rt * 16 + quad * 4 + reg;
                int col = wc * 32 + ct * 16 + l15;
                size_t o = ((size_t)(b * TLEN + n * CS + row)) * EDIM + e0 + col;
                out[o] = accT[rt][ct][reg] + x[o];
            }
        }
}

// ---------------------------------------------------------------------------
extern "C" void kernel_launch(void* const* d_in, const int* in_sizes, int n_in,
                              void* d_out, int out_size, void* d_ws, size_t ws_size,
                              hipStream_t stream) {
    const float* x  = (const float*)d_in[0];   // [2, 8192, 256] fp32
    const float* dp = (const float*)d_in[1];   // [128, 1024] fp32
    float* out = (float*)d_out;

    char* ws = (char*)d_ws;
    short* cn_hi  = (short*)(ws);                       // 8 MB
    short* cn_lo  = (short*)(ws + (8u << 20));          // 8 MB
    short* xt_hi  = (short*)(ws + (16u << 20));         // 8 MB
    short* dp_hi  = (short*)(ws + (24u << 20));         // 256 KB
    float* scores = (float*)(ws + (25u << 20));         // 32 KB

    prep_kernel <<<dim3(264), 256, 0, stream>>>(x, dp, cn_hi, cn_lo, xt_hi, dp_hi);
    scores_mfma <<<dim3(NCHUNK * (NCHUNK - 1) / 2, NBATCH), 256, 0, stream>>>(cn_hi, cn_lo, scores);
    out_mfma    <<<dim3(4, NCHUNK, NBATCH), 256, 0, stream>>>(x, dp_hi, xt_hi, scores, out);
}

// Round 3
// 202.922 us; speedup vs baseline: 1.0263x; 1.0263x over previous
//
#include <hip/hip_runtime.h>
#include <hip/hip_bf16.h>

// Problem constants (fixed by the reference)
#define CS     128
#define EDIM   256
#define NBATCH 2
#define TLEN   8192
#define NCHUNK 64
#define LEXT   1024
#define KSEL   7

typedef __attribute__((ext_vector_type(8)))  short short8;    // 8 bf16 = 4 VGPR (MFMA A/B frag)
typedef __attribute__((ext_vector_type(4)))  float floatx4;   // 16x16 MFMA C/D frag
typedef __attribute__((ext_vector_type(16))) float floatx16;  // 32x32 MFMA C/D frag

__device__ inline short bf16_of(float f) {
    __hip_bfloat16 h = __float2bfloat16(f);
    return *(short*)&h;
}
__device__ inline float f_of_bf16(short s) {
    __hip_bfloat16 h = *(__hip_bfloat16*)&s;
    return __bfloat162float(h);
}

// async global->LDS, 16B per lane; LDS dest = wave-uniform base + lane*16
__device__ inline void gl_lds16(const void* g, void* l) {
    __builtin_amdgcn_global_load_lds(
        (const __attribute__((address_space(1))) unsigned int*)g,
        (__attribute__((address_space(3))) unsigned int*)l, 16, 0, 0);
}

// raw barrier (no compiler vmcnt(0) drain) — counted vmcnt crosses it
#define RAW_BAR() asm volatile("s_barrier" ::: "memory")

// ---------------------------------------------------------------------------
// Fused prep: one x read -> cn_hi/cn_lo (k-sliced layout) + xt_hi ;
// 8 tail blocks convert dp.
// cn layout: [b][chunk 64][ks 16][row 128][k 16] shorts — each (ks) tile
// of a chunk is one contiguous 4 KB block, so scores' gl_lds staging is a
// contiguous copy (perfect coalescing).   (unchanged from round 2, passed)
// ---------------------------------------------------------------------------
__global__ __launch_bounds__(256) void prep_kernel(const float* __restrict__ x,
                                                   const float* __restrict__ dp,
                                                   short* __restrict__ cn_hi,
                                                   short* __restrict__ cn_lo,
                                                   short* __restrict__ xt_hi,
                                                   short* __restrict__ dp_hi) {
    const int bx = blockIdx.x;
    if (bx >= 256) {            // dp conversion: 8 blocks x 256 thr x 16 float4
        int t = (bx - 256) * 256 + threadIdx.x;
#pragma unroll
        for (int u = 0; u < 16; ++u) {
            int idx = (t * 16 + u) * 4;
            float4 v = *(const float4*)(dp + idx);
            *(short4*)(dp_hi + idx) =
                make_short4(bf16_of(v.x), bf16_of(v.y), bf16_of(v.z), bf16_of(v.w));
        }
        return;
    }

    __shared__ float tile[64 * 257];   // [t-row][e], pitch 257
    __shared__ float rnbuf[64];
    const int b = bx >> 7, t0 = (bx & 127) * 64;
    const int tid = threadIdx.x;
    const int r = tid >> 2, q = tid & 3;   // row r (0..63), quarter q (64 elems)

    const float* src = x + ((size_t)(b * TLEN + t0 + r)) * EDIM + q * 64;
    float* trow = &tile[r * 257 + q * 64];
    float s = 0.f;
#pragma unroll
    for (int u = 0; u < 16; ++u) {
        float4 v = *(const float4*)(src + u * 4);
        s += v.x * v.x + v.y * v.y + v.z * v.z + v.w * v.w;
        trow[u * 4 + 0] = v.x; trow[u * 4 + 1] = v.y;
        trow[u * 4 + 2] = v.z; trow[u * 4 + 3] = v.w;
    }
    s += __shfl_xor(s, 1);
    s += __shfl_xor(s, 2);
    const float rn = 1.0f / (sqrtf(s) + 1e-6f);
    if (q == 0) rnbuf[r] = rn;
    __syncthreads();

    // xt_hi write (layout [b][e][T])
    const int g16 = tid >> 4, tq = tid & 15;
#pragma unroll
    for (int it = 0; it < 16; ++it) {
        int e = g16 + it * 16;
        short hs2[4];
#pragma unroll
        for (int g = 0; g < 4; ++g)
            hs2[g] = bf16_of(tile[(tq * 4 + g) * 257 + e]);
        *(short4*)(xt_hi + ((size_t)(b * EDIM + e)) * TLEN + t0 + tq * 4)
            = make_short4(hs2[0], hs2[1], hs2[2], hs2[3]);
    }

    // cn write, k-sliced layout. thread (ks = tid>>4, l16 = tid&15) writes
    // rows l16, l16+16, l16+32, l16+48 of slice ks: 16 lanes x 32 B contiguous.
    const int chunk = t0 >> 7, half = (t0 >> 6) & 1;
    const size_t cbase = ((size_t)(b * 64 + chunk)) * 32768 + (size_t)half * 1024;
    const int ks = tid >> 4, l16 = tid & 15;
#pragma unroll
    for (int rr = 0; rr < 4; ++rr) {
        int lrow = rr * 16 + l16;
        float rnv = rnbuf[lrow];
        short8 h0, h1, l0, l1;
#pragma unroll
        for (int k2 = 0; k2 < 16; ++k2) {
            float c = tile[lrow * 257 + ks * 16 + k2] * rnv;
            short hh = bf16_of(c);
            short ll = bf16_of(c - f_of_bf16(hh));
            if (k2 < 8) { h0[k2] = hh; l0[k2] = ll; }
            else        { h1[k2 - 8] = hh; l1[k2 - 8] = ll; }
        }
        size_t o = cbase + (size_t)ks * 2048 + (size_t)lrow * 16;
        *(short8*)(cn_hi + o)     = h0;
        *(short8*)(cn_hi + o + 8) = h1;
        *(short8*)(cn_lo + o)     = l0;
        *(short8*)(cn_lo + o + 8) = l1;
    }
}

// ---------------------------------------------------------------------------
// Stage B v4: split-bf16 cosine scores, 32x32x16 MFMA, K-step 16, 4 blk/CU —
// round-2 structure + XOR granule swizzle to kill the measured 4-way bank
// conflict (8.26M cyc = 2048/block, same signature as pre-swizzle r12).
//
// Granule (16B) involution f(g) = g ^ ((g>>3)&1)  [XOR bit0 with row-bit2]:
//   - staging: LDS dest linear (gl_lds requirement); per-lane GLOBAL source
//     pre-swizzled lane -> lane ^ ((lane>>3)&1)  (both-sides-or-neither)
//   - frag read: granule = (row*2 + hi) ^ ((row>>2)&1)
// Result: every 16-lane quarter-wave spreads 2-per-4-bank-group = 2-way =
// free (m136). Register values bit-identical to round 2.
// C/D layout (verified, m74/m101): col = lane&31,
// row = (reg&3) + 8*(reg>>2) + 4*(lane>>5).
// ---------------------------------------------------------------------------
__global__ __launch_bounds__(256, 4) void scores_mfma(const short* __restrict__ cn_hi,
                                                      const short* __restrict__ cn_lo,
                                                      float* __restrict__ scores) {
    __shared__ short tiles[2][4][2048];         // [buf][Ah,Al,Bh,Bl][granule*8+k] 32 KB
    double* red2   = (double*)&tiles[0][0][0];  // alias (epilogue only)
    float*  redbuf = (float*)&tiles[0][0][8];   // alias, bytes [16, 1040)

    const int p = blockIdx.x, b = blockIdx.y;
    int i = (int)((1.0f + sqrtf(1.0f + 8.0f * (float)p)) * 0.5f);
    while (i * (i - 1) / 2 > p) --i;
    while (i * (i + 1) / 2 <= p) ++i;
    const int j = p - i * (i - 1) / 2;

    const int tid  = threadIdx.x;
    const int w    = tid >> 6, lane = tid & 63;
    const int wr   = w >> 1, wc = w & 1;
    const int hi   = lane >> 5, l31 = lane & 31;

    const short* sarr  = (w & 1) ? cn_lo : cn_hi;
    const size_t sbase = ((size_t)b * 64 + ((w >> 1) ? j : i)) * 32768;
    // staging source pre-swizzle: lane -> f(lane) (bit3 of t*32+lane == bit3 of lane)
    const short* gsrc0 = sarr + sbase + (size_t)((lane ^ ((lane >> 3) & 1)) * 8);

    // wave w stages its own 4 KB tile (Ah/Al/Bh/Bl) with 4 contiguous gl_lds
    auto stage = [&](int ks, int bf) {
        const short* g = gsrc0 + ks * 2048;
        short* ldst = &tiles[bf][w][0];
#pragma unroll
        for (int t = 0; t < 4; ++t)
            gl_lds16(g + t * 512, ldst + t * 512);
    };

    floatx16 acc[2][2];
#pragma unroll
    for (int rt = 0; rt < 2; ++rt)
#pragma unroll
        for (int ct = 0; ct < 2; ++ct)
#pragma unroll
            for (int reg = 0; reg < 16; ++reg) acc[rt][ct][reg] = 0.f;

    stage(0, 0);
    int buf = 0;
    for (int ks = 0; ks < 16; ++ks) {
        if (ks < 15) {
            stage(ks + 1, buf ^ 1);                           // 4 loads in flight
            asm volatile("s_waitcnt vmcnt(4)" ::: "memory");  // old 4 landed
        } else {
            asm volatile("s_waitcnt vmcnt(0)" ::: "memory");
        }
        RAW_BAR();   // all waves' current-buf tiles have landed

        short8 bh[2], bl[2];
#pragma unroll
        for (int ct = 0; ct < 2; ++ct) {
            int rb = wc * 64 + ct * 32 + l31;
            int gb = ((rb * 2 + hi) ^ ((rb >> 2) & 1)) * 8;   // swizzled granule
            bh[ct] = *(const short8*)&tiles[buf][2][gb];
            bl[ct] = *(const short8*)&tiles[buf][3][gb];
        }
        __builtin_amdgcn_s_setprio(1);
#pragma unroll
        for (int rt = 0; rt < 2; ++rt) {
            int ra = wr * 64 + rt * 32 + l31;
            int ga = ((ra * 2 + hi) ^ ((ra >> 2) & 1)) * 8;   // swizzled granule
            short8 ah = *(const short8*)&tiles[buf][0][ga];
            short8 al = *(const short8*)&tiles[buf][1][ga];
#pragma unroll
            for (int ct = 0; ct < 2; ++ct) {
                acc[rt][ct] = __builtin_amdgcn_mfma_f32_32x32x16_bf16(ah, bh[ct], acc[rt][ct], 0, 0, 0);
                acc[rt][ct] = __builtin_amdgcn_mfma_f32_32x32x16_bf16(ah, bl[ct], acc[rt][ct], 0, 0, 0);
                acc[rt][ct] = __builtin_amdgcn_mfma_f32_32x32x16_bf16(al, bh[ct], acc[rt][ct], 0, 0, 0);
            }
        }
        __builtin_amdgcn_s_setprio(0);
        RAW_BAR();   // all waves done reading buf before next stage overwrites
        buf ^= 1;
    }

    // epilogue: per-row max over 128 cols, then sum of row-maxes
#pragma unroll
    for (int rt = 0; rt < 2; ++rt) {
        float m[16];
#pragma unroll
        for (int reg = 0; reg < 16; ++reg)
            m[reg] = fmaxf(acc[rt][0][reg], acc[rt][1][reg]);
#pragma unroll
        for (int off = 1; off < 32; off <<= 1)
#pragma unroll
            for (int reg = 0; reg < 16; ++reg)
                m[reg] = fmaxf(m[reg], __shfl_xor(m[reg], off));
        if ((lane & 31) == 0) {
#pragma unroll
            for (int reg = 0; reg < 16; ++reg) {
                int rowin = (reg & 3) + 8 * (reg >> 2) + 4 * hi;
                redbuf[wc * 128 + wr * 64 + rt * 32 + rowin] = m[reg];
            }
        }
    }
    __syncthreads();

    double part = 0.0;
    if (tid < 128) part = (double)fmaxf(redbuf[tid], redbuf[128 + tid]);
#pragma unroll
    for (int off = 1; off < 64; off <<= 1) part += __shfl_xor(part, off);
    if (lane == 0 && w < 2) red2[w] = part;
    __syncthreads();
    if (tid == 0) scores[(b * NCHUNK + i) * NCHUNK + j] = (float)(red2[0] + red2[1]);
}

// ---------------------------------------------------------------------------
// Stage D v7: out = dp @ ext + chunk, single-pass bf16 MFMA, inlined top-k.
// K=64 steps (2 k32 sub-slices each), 3 LDS buffers, prefetch depth 2,
// ONE raw barrier per step. Counted per-wave vmcnt. (unchanged from round 2)
// ---------------------------------------------------------------------------
__global__ __launch_bounds__(256) void out_mfma(const float* __restrict__ x,
                                                const short* __restrict__ dph,
                                                const short* __restrict__ xth,
                                                const float* __restrict__ scores,
                                                float* __restrict__ out) {
    __shared__ short As[3][2][128 * 32];   // [buf][sub][c][k]  48 KB
    __shared__ short Bs[3][2][64 * 32];    // [buf][sub][e][k]  24 KB
    __shared__ int   slist[8], sslot[8], snum;
    __shared__ float swei[8];

    const int eq = blockIdx.x, n = blockIdx.y, b = blockIdx.z;
    const int e0 = eq * 64;
    const int tid  = threadIdx.x;
    const int w    = tid >> 6, lane = tid & 63;
    const int wr   = w >> 1, wc = w & 1;
    const int quad = lane >> 4, l15 = lane & 15;
    const int rr   = lane >> 2;
    const int c16  = (lane & 3) * 8;
    const int csw  = c16 ^ (((rr >> 1) & 3) * 8);
    const int q8   = (quad ^ ((l15 >> 1) & 3)) * 8;

    // ---- inlined top-7 (wave 0): candidates j in [0, n) ----
    if (w == 0) {
        const float* srow = scores + (b * NCHUNK + n) * NCHUNK;
        const int nsel = n < KSEL ? n : KSEL;
        float v = (lane < n) ? srow[lane] : -3.0e38f;
        float vals[KSEL];
        int   idxs[KSEL];
        for (int s2 = 0; s2 < nsel; ++s2) {
            float bv = v; int bi = lane;
#pragma unroll
            for (int off = 1; off < 64; off <<= 1) {
                float ov = __shfl_xor(bv, off);
                int   oi = __shfl_xor(bi, off);
                if (ov > bv || (ov == bv && oi < bi)) { bv = ov; bi = oi; }
            }
            vals[s2] = bv; idxs[s2] = bi;
            if (lane == bi) v = -3.0e38f;
        }
        if (lane == 0) {
            float vmin = (nsel > 0) ? vals[nsel - 1] : 0.0f;
            float inv  = 1.0f / (vmin + 1e-6f);
            int shift  = KSEL - nsel;
            int c = 0;
            for (int s2 = 0; s2 < 8; ++s2) {
                int jj; float ww;
                if (s2 < KSEL) {
                    int tt = s2 - shift;
                    if (tt >= 0) { jj = idxs[tt]; ww = vals[tt] * inv; }
                    else         { jj = -1;       ww = 0.0f; }
                } else { jj = n; ww = 1.0f; }
                if (jj >= 0) { slist[c] = jj; sslot[c] = s2; swei[c] = ww; ++c; }
            }
            snum = c;
        }
    }
    __syncthreads();
    const int NT = snum * 2;   // K=64 steps (2 k32 sub-slices per step)

    // stage step st into buffer b3: waves 0-1 stage As (8 loads), 2-3 Bs (4)
    auto stage = [&](int st, int b3) {
        int sv = st >> 1, kh = st & 1;
        if (w < 2) {
#pragma unroll
            for (int sub = 0; sub < 2; ++sub) {
                const short* gsrc = dph + (size_t)(sslot[sv] * 128 + (kh * 2 + sub) * 32) + csw;
#pragma unroll
                for (int t = 0; t < 4; ++t)
                    gl_lds16(gsrc + (size_t)(w * 64 + t * 16 + rr) * LEXT,
                             &As[b3][sub][(w * 64 + t * 16) * 32]);
            }
        } else {
#pragma unroll
            for (int sub = 0; sub < 2; ++sub) {
                const short* gsrc = xth + ((size_t)(b * EDIM + e0)) * TLEN
                                    + (size_t)(slist[sv] * CS + (kh * 2 + sub) * 32) + csw;
#pragma unroll
                for (int t = 0; t < 2; ++t)
                    gl_lds16(gsrc + (size_t)((w - 2) * 32 + t * 16 + rr) * TLEN,
                             &Bs[b3][sub][((w - 2) * 32 + t * 16) * 32]);
            }
        }
    };

    floatx4 accT[4][2], accP[4][2];
#pragma unroll
    for (int rt = 0; rt < 4; ++rt)
#pragma unroll
        for (int ct = 0; ct < 2; ++ct) accT[rt][ct] = (floatx4){0.f, 0.f, 0.f, 0.f};

    stage(0, 0);
    if (NT > 1) stage(1, 1);
    // ensure stage 0 landed (allow stage 1's loads to remain in flight)
    if (w < 2) asm volatile("s_waitcnt vmcnt(8)" ::: "memory");
    else       asm volatile("s_waitcnt vmcnt(4)" ::: "memory");

    int cur = 0;
    for (int st = 0; st < NT; ++st) {
        RAW_BAR();   // all waves: buf 'cur' landed, and compute(st-1) finished

        if ((st & 1) == 0) {
#pragma unroll
            for (int rt = 0; rt < 4; ++rt)
#pragma unroll
                for (int ct = 0; ct < 2; ++ct) accP[rt][ct] = (floatx4){0.f, 0.f, 0.f, 0.f};
        }

#pragma unroll
        for (int sub = 0; sub < 2; ++sub) {
            short8 bh[2];
#pragma unroll
            for (int ct = 0; ct < 2; ++ct) {
                int e = wc * 32 + ct * 16 + l15;
                bh[ct] = *(const short8*)&Bs[cur][sub][e * 32 + q8];
            }
            __builtin_amdgcn_s_setprio(1);
#pragma unroll
            for (int rt = 0; rt < 4; ++rt) {
                int r = wr * 64 + rt * 16 + l15;
                short8 ah = *(const short8*)&As[cur][sub][r * 32 + q8];
#pragma unroll
                for (int ct = 0; ct < 2; ++ct)
                    accP[rt][ct] = __builtin_amdgcn_mfma_f32_16x16x32_bf16(ah, bh[ct], accP[rt][ct], 0, 0, 0);
            }
            __builtin_amdgcn_s_setprio(0);
        }

        if ((st & 1) == 1) {
            float wcur = swei[st >> 1];
#pragma unroll
            for (int rt = 0; rt < 4; ++rt)
#pragma unroll
                for (int ct = 0; ct < 2; ++ct)
#pragma unroll
                    for (int reg = 0; reg < 4; ++reg)
                        accT[rt][ct][reg] += wcur * accP[rt][ct][reg];
        }

        if (st + 2 < NT) {
            int tgt = cur ? cur - 1 : 2;        // (cur+2)%3
            stage(st + 2, tgt);
            if (w < 2) asm volatile("s_waitcnt vmcnt(8)" ::: "memory");
            else       asm volatile("s_waitcnt vmcnt(4)" ::: "memory");
        } else if (st + 1 < NT) {
            asm volatile("s_waitcnt vmcnt(0)" ::: "memory");
        }
        cur = (cur == 2) ? 0 : cur + 1;
    }

#pragma unroll
    for (int rt = 0; rt < 4; ++rt)
#pragma unroll
        for (int ct = 0; ct < 2; ++ct) {
#pragma unroll
            for (int reg = 0; reg < 4; ++reg) {
                int row = wr * 64 + rt * 16 + quad * 4 + reg;
                int col = wc * 32 + ct * 16 + l15;
                size_t o = ((size_t)(b * TLEN + n * CS + row)) * EDIM + e0 + col;
                out[o] = accT[rt][ct][reg] + x[o];
            }
        }
}

// ---------------------------------------------------------------------------
extern "C" void kernel_launch(void* const* d_in, const int* in_sizes, int n_in,
                              void* d_out, int out_size, void* d_ws, size_t ws_size,
                              hipStream_t stream) {
    const float* x  = (const float*)d_in[0];   // [2, 8192, 256] fp32
    const float* dp = (const float*)d_in[1];   // [128, 1024] fp32
    float* out = (float*)d_out;

    char* ws = (char*)d_ws;
    short* cn_hi  = (short*)(ws);                       // 8 MB
    short* cn_lo  = (short*)(ws + (8u << 20));          // 8 MB
    short* xt_hi  = (short*)(ws + (16u << 20));         // 8 MB
    short* dp_hi  = (short*)(ws + (24u << 20));         // 256 KB
    float* scores = (float*)(ws + (25u << 20));         // 32 KB

    prep_kernel <<<dim3(264), 256, 0, stream>>>(x, dp, cn_hi, cn_lo, xt_hi, dp_hi);
    scores_mfma <<<dim3(NCHUNK * (NCHUNK - 1) / 2, NBATCH), 256, 0, stream>>>(cn_hi, cn_lo, scores);
    out_mfma    <<<dim3(4, NCHUNK, NBATCH), 256, 0, stream>>>(x, dp_hi, xt_hi, scores, out);
}